// Round 7
// baseline (628.253 us; speedup 1.0000x reference)
//
#include <hip/hip_runtime.h>

typedef __attribute__((ext_vector_type(8))) short bf16x8;
typedef __attribute__((ext_vector_type(4))) float f32x4;

__device__ __forceinline__ unsigned short f2bf(float f) {
    unsigned u = __float_as_uint(f);
    unsigned r = (u + 0x7FFFu + ((u >> 16) & 1u)) >> 16;   // RNE
    return (unsigned short)r;
}

__device__ __forceinline__ void gload16(const unsigned short* g, unsigned short* l) {
    __builtin_amdgcn_global_load_lds((const __attribute__((address_space(1))) void*)g,
                                     (__attribute__((address_space(3))) void*)l, 16, 0, 0);
}

#define BARRIER() do { asm volatile("" ::: "memory"); __builtin_amdgcn_s_barrier(); asm volatile("" ::: "memory"); } while (0)

// ---------------- conversion kernels ----------------

__global__ void conv_x_kernel(const float* __restrict__ x, unsigned short* __restrict__ xb, int total8) {
    int i = blockIdx.x * blockDim.x + threadIdx.x;
    if (i >= total8) return;
    const float4* xv = (const float4*)x;
    float4 a = xv[(size_t)i * 2];
    float4 b = xv[(size_t)i * 2 + 1];
    uint4 o;
    o.x = (unsigned)f2bf(a.x) | ((unsigned)f2bf(a.y) << 16);
    o.y = (unsigned)f2bf(a.z) | ((unsigned)f2bf(a.w) << 16);
    o.z = (unsigned)f2bf(b.x) | ((unsigned)f2bf(b.y) << 16);
    o.w = (unsigned)f2bf(b.z) | ((unsigned)f2bf(b.w) << 16);
    ((uint4*)xb)[i] = o;
}

__global__ void conv_c_kernel(const float* __restrict__ c, unsigned short* __restrict__ cb,
                              float* __restrict__ c2, unsigned long long* __restrict__ packed,
                              int N, int D) {
    int k = blockIdx.x;
    int tid = threadIdx.x;                      // 256 threads, 4 elems each
    const float4 v = ((const float4*)(c + (long)k * D))[tid];
    uint2 o;
    o.x = (unsigned)f2bf(v.x) | ((unsigned)f2bf(v.y) << 16);
    o.y = (unsigned)f2bf(v.z) | ((unsigned)f2bf(v.w) << 16);
    ((uint2*)(cb + (long)k * D))[tid] = o;
    float s = v.x * v.x + v.y * v.y + v.z * v.z + v.w * v.w;
    #pragma unroll
    for (int d = 1; d < 64; d <<= 1) s += __shfl_xor(s, d, 64);
    __shared__ float wsum[4];
    int lane = tid & 63, w = tid >> 6;
    if (lane == 0) wsum[w] = s;
    __syncthreads();
    if (tid == 0) c2[k] = wsum[0] + wsum[1] + wsum[2] + wsum[3];
    int gid = k * 256 + tid;
    if (gid < N) packed[gid] = ~0ull;
}

// ------------- REAL GEMM + argmin (verbatim round-6 ring-of-4) -------------
__global__ void __launch_bounds__(512, 2)
gemm_argmin_kernel(const unsigned short* __restrict__ Xb,
                   const unsigned short* __restrict__ Cb,
                   const float* __restrict__ c2,
                   unsigned long long* __restrict__ packed,
                   int D, int nt) {
    __shared__ unsigned short sh[65536];       // 128 KiB
    const int tid  = threadIdx.x;
    const int lane = tid & 63;
    const int w    = tid >> 6;
    const int wr   = w >> 2;
    const int wc   = w & 3;
    const long rowbase = (long)blockIdx.x * 256;
    const int  colbase = blockIdx.y * 256;
    const int fr = lane & 15;
    const int g  = lane >> 4;

    const int c0 = tid, c1 = 512 + tid;
    const unsigned short* gA0 = Xb + (rowbase + (c0 >> 2)) * D + (c0 & 3) * 8;
    const unsigned short* gA1 = Xb + (rowbase + (c1 >> 2)) * D + (c1 & 3) * 8;
    const unsigned short* gB0 = Cb + ((long)colbase + (c0 >> 2)) * D + (c0 & 3) * 8;
    const unsigned short* gB1 = Cb + ((long)colbase + (c1 >> 2)) * D + (c1 & 3) * 8;

    f32x4 acc[8][4] = {};
    bf16x8 a[8], b[4];

    auto stage = [&](int kt) {
        const int s = (kt & 3) * 8192;
        const long ko = (long)kt * 32;
        gload16(gA0 + ko, sh + s + c0 * 8);
        gload16(gA1 + ko, sh + s + c1 * 8);
        gload16(gB0 + ko, sh + 32768 + s + c0 * 8);
        gload16(gB1 + ko, sh + 32768 + s + c1 * 8);
    };

    stage(0); stage(1); stage(2);
    asm volatile("s_waitcnt vmcnt(8)" ::: "memory");
    BARRIER();

    for (int t = 0; t < nt; ++t) {
        const int sb = (t & 3) * 8192;
        if (t + 3 < nt) stage(t + 3);
        const int ar = sb + (wr * 128 + fr) * 32 + g * 8;
        #pragma unroll
        for (int m = 0; m < 8; ++m) a[m] = *(const bf16x8*)&sh[ar + m * 512];
        const int br = 32768 + sb + (wc * 64 + fr) * 32 + g * 8;
        #pragma unroll
        for (int n = 0; n < 4; ++n) b[n] = *(const bf16x8*)&sh[br + n * 512];
        asm volatile("s_waitcnt vmcnt(8) lgkmcnt(0)" ::: "memory");
        BARRIER();
        __builtin_amdgcn_s_setprio(1);
        #pragma unroll
        for (int m = 0; m < 8; ++m)
            #pragma unroll
            for (int n = 0; n < 4; ++n)
                acc[m][n] = __builtin_amdgcn_mfma_f32_16x16x32_bf16(a[m], b[n], acc[m][n], 0, 0, 0);
        __builtin_amdgcn_s_setprio(0);
    }

    float c2v[4];
    int   kcol[4];
    #pragma unroll
    for (int n = 0; n < 4; ++n) {
        kcol[n] = colbase + wc * 64 + n * 16 + fr;
        c2v[n]  = c2[kcol[n]];
    }
    #pragma unroll
    for (int m = 0; m < 8; ++m) {
        #pragma unroll
        for (int reg = 0; reg < 4; ++reg) {
            unsigned long long best = ~0ull;
            #pragma unroll
            for (int n = 0; n < 4; ++n) {
                float score = c2v[n] - 2.0f * acc[m][n][reg];
                unsigned u = __float_as_uint(score);
                u ^= (u >> 31) ? 0xFFFFFFFFu : 0x80000000u;
                unsigned long long cand = ((unsigned long long)u << 32) | (unsigned)kcol[n];
                best = cand < best ? cand : best;
            }
            #pragma unroll
            for (int s = 1; s < 16; s <<= 1) {
                unsigned long long other = __shfl_xor(best, s, 64);
                best = other < best ? other : best;
            }
            if (fr == 0) {
                long row = rowbase + wr * 128 + m * 16 + g * 4 + reg;
                atomicMin(&packed[row], best);
            }
        }
    }
}

// ------------- ABLATION PROBES (timing only; outputs -> dead scratch) -------------
// V0: full   V1: stage+MFMA (no ds_read)   V2: ds_read+MFMA (no stage)
// V3: MFMA+barriers only                   V4: stage+ds_read (no MFMA)
// nt=160 (K wrapped &31) to outrank the real 43us dispatch in the top-5 table.
template<int V>
__global__ void __launch_bounds__(512, 2)
gemm_probe_kernel(const unsigned short* __restrict__ Xb,
                  const unsigned short* __restrict__ Cb,
                  const float* __restrict__ c2,
                  unsigned long long* __restrict__ packed,
                  int D, int nt) {
    constexpr bool DO_STAGE = (V == 0) || (V == 1) || (V == 4);
    constexpr bool DO_READ  = (V == 0) || (V == 2) || (V == 4);
    constexpr bool DO_MFMA  = (V != 4);
    __shared__ unsigned short sh[65536];
    const int tid  = threadIdx.x;
    const int lane = tid & 63;
    const int w    = tid >> 6;
    const int wr   = w >> 2;
    const int wc   = w & 3;
    const long rowbase = (long)blockIdx.x * 256;
    const int  colbase = blockIdx.y * 256;
    const int fr = lane & 15;
    const int g  = lane >> 4;

    const int c0 = tid, c1 = 512 + tid;
    const unsigned short* gA0 = Xb + (rowbase + (c0 >> 2)) * D + (c0 & 3) * 8;
    const unsigned short* gA1 = Xb + (rowbase + (c1 >> 2)) * D + (c1 & 3) * 8;
    const unsigned short* gB0 = Cb + ((long)colbase + (c0 >> 2)) * D + (c0 & 3) * 8;
    const unsigned short* gB1 = Cb + ((long)colbase + (c1 >> 2)) * D + (c1 & 3) * 8;

    f32x4 acc[8][4] = {};
    bf16x8 a[8] = {};
    bf16x8 b[4] = {};

    auto stage = [&](int kt) {
        const int s = (kt & 3) * 8192;
        const long ko = (long)(kt & 31) * 32;     // wrap K for long probes
        gload16(gA0 + ko, sh + s + c0 * 8);
        gload16(gA1 + ko, sh + s + c1 * 8);
        gload16(gB0 + ko, sh + 32768 + s + c0 * 8);
        gload16(gB1 + ko, sh + 32768 + s + c1 * 8);
    };

    if constexpr (DO_STAGE) {
        stage(0); stage(1); stage(2);
        asm volatile("s_waitcnt vmcnt(8)" ::: "memory");
    }
    BARRIER();

    for (int t = 0; t < nt; ++t) {
        const int sb = (t & 3) * 8192;
        if constexpr (DO_STAGE) { if (t + 3 < nt) stage(t + 3); }
        if constexpr (DO_READ) {
            const int ar = sb + (wr * 128 + fr) * 32 + g * 8;
            #pragma unroll
            for (int m = 0; m < 8; ++m) a[m] = *(const bf16x8*)&sh[ar + m * 512];
            const int br = 32768 + sb + (wc * 64 + fr) * 32 + g * 8;
            #pragma unroll
            for (int n = 0; n < 4; ++n) b[n] = *(const bf16x8*)&sh[br + n * 512];
        }
        if constexpr (DO_STAGE && DO_READ)
            asm volatile("s_waitcnt vmcnt(8) lgkmcnt(0)" ::: "memory");
        else if constexpr (DO_STAGE)
            asm volatile("s_waitcnt vmcnt(8)" ::: "memory");
        else if constexpr (DO_READ)
            asm volatile("s_waitcnt lgkmcnt(0)" ::: "memory");
        BARRIER();
        if constexpr (DO_MFMA) {
            __builtin_amdgcn_s_setprio(1);
            #pragma unroll
            for (int m = 0; m < 8; ++m)
                #pragma unroll
                for (int n = 0; n < 4; ++n)
                    acc[m][n] = __builtin_amdgcn_mfma_f32_16x16x32_bf16(a[m], b[n], acc[m][n], 0, 0, 0);
            __builtin_amdgcn_s_setprio(0);
        } else {
            #pragma unroll
            for (int m = 0; m < 8; ++m) asm volatile("" :: "v"(a[m]));   // keep reads live
            #pragma unroll
            for (int n = 0; n < 4; ++n) asm volatile("" :: "v"(b[n]));
        }
    }

    // keep everything live via the real epilogue (writes to dead scratch)
    float c2v[4];
    int   kcol[4];
    #pragma unroll
    for (int n = 0; n < 4; ++n) {
        kcol[n] = colbase + wc * 64 + n * 16 + fr;
        c2v[n]  = c2[kcol[n]];
    }
    #pragma unroll
    for (int m = 0; m < 8; ++m) {
        #pragma unroll
        for (int reg = 0; reg < 4; ++reg) {
            unsigned long long best = ~0ull;
            #pragma unroll
            for (int n = 0; n < 4; ++n) {
                float score = c2v[n] - 2.0f * acc[m][n][reg];
                unsigned u = __float_as_uint(score);
                u ^= (u >> 31) ? 0xFFFFFFFFu : 0x80000000u;
                unsigned long long cand = ((unsigned long long)u << 32) | (unsigned)kcol[n];
                best = cand < best ? cand : best;
            }
            #pragma unroll
            for (int s = 1; s < 16; s <<= 1) {
                unsigned long long other = __shfl_xor(best, s, 64);
                best = other < best ? other : best;
            }
            if (fr == 0) {
                long row = rowbase + wr * 128 + m * 16 + g * 4 + reg;
                atomicMin(&packed[row], best);
            }
        }
    }
}

__global__ void extract16_kernel(const unsigned long long* __restrict__ p,
                                 unsigned short* __restrict__ lab, int n) {
    int i = blockIdx.x * blockDim.x + threadIdx.x;
    if (i < n) lab[i] = (unsigned short)(p[i] & 0xFFFFull);
}

// ---------------- segmented sum: sliced partials (S=4, u16 labels) ----------------
__global__ void segsum_partial_kernel(const unsigned short* __restrict__ lab,
                                      const float* __restrict__ emb,
                                      float* __restrict__ partial,
                                      int* __restrict__ pcount,
                                      int N, int D) {
    const int k   = blockIdx.x;
    const int s   = blockIdx.y;
    const int tid = threadIdx.x;
    const int grp = tid >> 8;
    const int ct  = tid & 255;
    const int lane = tid & 63, w = tid >> 6;

    __shared__ int idxbuf[4096];
    __shared__ int cnts[16];
    __shared__ float4 red[4][256];

    const int slice = N >> 2;
    const int base0 = s * slice;
    int total = 0;
    for (int base = base0; base < base0 + slice; base += 1024) {
        const int n = base + tid;
        const bool m = (lab[n] == (unsigned short)k);
        const unsigned long long bal = __ballot(m);
        if (lane == 0) cnts[w] = (int)__popcll(bal);
        __syncthreads();
        int myoff = total, run = total;
        #pragma unroll
        for (int w2 = 0; w2 < 16; ++w2) {
            if (w2 == w) myoff = run;
            run += cnts[w2];
        }
        if (m) idxbuf[myoff + (int)__popcll(bal & ((1ull << lane) - 1ull))] = n;
        total = run;
        __syncthreads();
    }

    float4 acc = {0.f, 0.f, 0.f, 0.f};
    for (int j = grp; j < total; j += 4) {
        const int row = idxbuf[j];
        const float4 v = *(const float4*)(emb + (long)row * D + ct * 4);
        acc.x += v.x; acc.y += v.y; acc.z += v.z; acc.w += v.w;
    }
    red[grp][ct] = acc;
    __syncthreads();
    if (grp == 0) {
        float4 r = red[0][ct];
        #pragma unroll
        for (int q = 1; q < 4; ++q) {
            const float4 v = red[q][ct];
            r.x += v.x; r.y += v.y; r.z += v.z; r.w += v.w;
        }
        *(float4*)(partial + ((long)(k * 4 + s)) * D + ct * 4) = r;
    }
    if (tid == 0) pcount[k * 4 + s] = total;
}

__global__ void finalize_kernel(const float* __restrict__ partial,
                                const int* __restrict__ pcount,
                                const float* __restrict__ centers,
                                const int* __restrict__ cnt,
                                float* __restrict__ out, int D) {
    const int k = blockIdx.x;
    const int ct = threadIdx.x;
    float4 acc = {0.f, 0.f, 0.f, 0.f};
    int mtot = 0;
    #pragma unroll
    for (int s = 0; s < 4; ++s) {
        const float4 p = *(const float4*)(partial + ((long)(k * 4 + s)) * D + ct * 4);
        acc.x += p.x; acc.y += p.y; acc.z += p.z; acc.w += p.w;
        mtot += pcount[k * 4 + s];
    }
    const float4 cv = *(const float4*)(centers + (long)k * D + ct * 4);
    float4 o;
    if (mtot > 0) {
        float ccn = 0.5f * (float)cnt[k] + 0.5f * (float)mtot;
        float lr  = 1.0f / (ccn + 1.0f);
        float im  = 1.0f / (float)mtot;
        float om  = 1.0f - lr;
        o.x = om * cv.x + lr * (acc.x * im);
        o.y = om * cv.y + lr * (acc.y * im);
        o.z = om * cv.z + lr * (acc.z * im);
        o.w = om * cv.w + lr * (acc.w * im);
    } else {
        o = cv;
    }
    *(float4*)(out + (long)k * D + ct * 4) = o;
}

// ---------------- launch ----------------

extern "C" void kernel_launch(void* const* d_in, const int* in_sizes, int n_in,
                              void* d_out, int out_size, void* d_ws, size_t ws_size,
                              hipStream_t stream) {
    const float* emb = (const float*)d_in[0];
    const float* cen = (const float*)d_in[1];
    const int*   cnt = (const int*)d_in[2];
    float* out = (float*)d_out;
    const int K = in_sizes[2];
    const int D = in_sizes[1] / K;      // 1024
    const int N = in_sizes[0] / D;      // 16384

    char* ws = (char*)d_ws;
    size_t xb_bytes = (size_t)N * D * 2;            // 32 MB
    size_t cb_bytes = (size_t)K * D * 2;            // 2 MB
    unsigned short* Xb = (unsigned short*)ws;
    unsigned short* Cb = (unsigned short*)(ws + xb_bytes);
    float* c2 = (float*)(ws + xb_bytes + cb_bytes);
    unsigned long long* packed = (unsigned long long*)(ws + xb_bytes + cb_bytes + (size_t)K * 4);
    unsigned short* lab16 = (unsigned short*)(ws + xb_bytes + cb_bytes + (size_t)K * 4 + (size_t)N * 8);
    int* pcount = (int*)(ws + xb_bytes + cb_bytes + (size_t)K * 4 + (size_t)N * 8 + (size_t)N * 2);
    unsigned long long* probe_packed = (unsigned long long*)(ws + xb_bytes + cb_bytes + (size_t)K * 4 +
                                                             (size_t)N * 8 + (size_t)N * 2 + (size_t)K * 16);
    float* partial = (float*)ws;   // aliases Xb (dead after gemm+probes)

    int total8 = N * D / 8;
    conv_x_kernel<<<dim3((total8 + 255) / 256), dim3(256), 0, stream>>>(emb, Xb, total8);
    conv_c_kernel<<<dim3(K), dim3(256), 0, stream>>>(cen, Cb, c2, packed, N, D);
    gemm_argmin_kernel<<<dim3(N / 256, K / 256), dim3(512), 0, stream>>>(Xb, Cb, c2, packed, D, D / 32);
    // ---- ablation probes (read Xb/Cb before segsum overwrites; write dead scratch) ----
    gemm_probe_kernel<1><<<dim3(N / 256, K / 256), dim3(512), 0, stream>>>(Xb, Cb, c2, probe_packed, D, 160);
    gemm_probe_kernel<2><<<dim3(N / 256, K / 256), dim3(512), 0, stream>>>(Xb, Cb, c2, probe_packed, D, 160);
    gemm_probe_kernel<3><<<dim3(N / 256, K / 256), dim3(512), 0, stream>>>(Xb, Cb, c2, probe_packed, D, 160);
    gemm_probe_kernel<4><<<dim3(N / 256, K / 256), dim3(512), 0, stream>>>(Xb, Cb, c2, probe_packed, D, 160);
    gemm_probe_kernel<0><<<dim3(8, K / 256), dim3(512), 0, stream>>>(Xb, Cb, c2, probe_packed, D, 160);
    // ---- real pipeline continues ----
    extract16_kernel<<<dim3((N + 255) / 256), dim3(256), 0, stream>>>(packed, lab16, N);
    segsum_partial_kernel<<<dim3(K, 4), dim3(1024), 0, stream>>>(lab16, emb, partial, pcount, N, D);
    finalize_kernel<<<dim3(K), dim3(256), 0, stream>>>(partial, pcount, cen, cnt, out, D);
}

// Round 8
// 118.211 us; speedup vs baseline: 5.3147x; 5.3147x over previous
//
#include <hip/hip_runtime.h>

typedef __attribute__((ext_vector_type(8))) short bf16x8;
typedef __attribute__((ext_vector_type(4))) float f32x4;

__device__ __forceinline__ unsigned short f2bf(float f) {
    unsigned u = __float_as_uint(f);
    unsigned r = (u + 0x7FFFu + ((u >> 16) & 1u)) >> 16;   // RNE
    return (unsigned short)r;
}

__device__ __forceinline__ void gload16(const unsigned short* g, unsigned short* l) {
    __builtin_amdgcn_global_load_lds((const __attribute__((address_space(1))) void*)g,
                                     (__attribute__((address_space(3))) void*)l, 16, 0, 0);
}

#define BARRIER() do { asm volatile("" ::: "memory"); __builtin_amdgcn_s_barrier(); asm volatile("" ::: "memory"); } while (0)

// ---------------- conversion kernels ----------------

__global__ void conv_x_kernel(const float* __restrict__ x, unsigned short* __restrict__ xb, int total8) {
    int i = blockIdx.x * blockDim.x + threadIdx.x;
    if (i >= total8) return;
    const float4* xv = (const float4*)x;
    float4 a = xv[(size_t)i * 2];
    float4 b = xv[(size_t)i * 2 + 1];
    uint4 o;
    o.x = (unsigned)f2bf(a.x) | ((unsigned)f2bf(a.y) << 16);
    o.y = (unsigned)f2bf(a.z) | ((unsigned)f2bf(a.w) << 16);
    o.z = (unsigned)f2bf(b.x) | ((unsigned)f2bf(b.y) << 16);
    o.w = (unsigned)f2bf(b.z) | ((unsigned)f2bf(b.w) << 16);
    ((uint4*)xb)[i] = o;
}

__global__ void conv_c_kernel(const float* __restrict__ c, unsigned short* __restrict__ cb,
                              float* __restrict__ c2, unsigned long long* __restrict__ packed,
                              int N, int D) {
    int k = blockIdx.x;
    int tid = threadIdx.x;                      // 256 threads, 4 elems each
    const float4 v = ((const float4*)(c + (long)k * D))[tid];
    uint2 o;
    o.x = (unsigned)f2bf(v.x) | ((unsigned)f2bf(v.y) << 16);
    o.y = (unsigned)f2bf(v.z) | ((unsigned)f2bf(v.w) << 16);
    ((uint2*)(cb + (long)k * D))[tid] = o;
    float s = v.x * v.x + v.y * v.y + v.z * v.z + v.w * v.w;
    #pragma unroll
    for (int d = 1; d < 64; d <<= 1) s += __shfl_xor(s, d, 64);
    __shared__ float wsum[4];
    int lane = tid & 63, w = tid >> 6;
    if (lane == 0) wsum[w] = s;
    __syncthreads();
    if (tid == 0) c2[k] = wsum[0] + wsum[1] + wsum[2] + wsum[3];
    int gid = k * 256 + tid;
    if (gid < N) packed[gid] = ~0ull;
}

// ------------- GEMM + argmin : 256x256, BK=32, ring-of-3, port-balanced -------------
// LDS 96 KiB: A slots 3x16KB (ushort idx slot*8192), B slots 3x16KB at 24576+slot*8192.
// Layout (both A and B): logical (row 0..255, q 0..3 of 16B) -> line=row>>1,
//   s_phys = ((row&1)*4 + q) ^ (line&7), ushort addr = line*64 + s_phys*8.
//   Conflict-free for frag reads (64 lanes hit 64 distinct 16B slots) and writes.
// A staged via regs (global->VGPR->ds_write_b128, fast 128B/cyc LDS port);
// B staged via gload_lds with PRE-SWIZZLED global source (linear LDS dest, m173).
// Pipeline at tile t: issue gloadB(t+2), loadA(t+3)->regs; head-read b(t), a47(t);
// ahead-read a03(t+1) (drains under MFMA, compiler-counted lgkm); 32xMFMA;
// writeA(t+2) (compiler auto-vmcnt retires A(t+2) AND older B(t+1) -> cross-wave
// safety for next tile's b-read); lgkmcnt(0); BARRIER (one per tile).
// Slot use at tile t: read t%3 (b,a47), read (t+1)%3 (a03), write (t+2)%3 -- disjoint.
template<int NT>
__global__ void __launch_bounds__(512, 2)
gemm_argmin_kernel(const unsigned short* __restrict__ Xb,
                   const unsigned short* __restrict__ Cb,
                   const float* __restrict__ c2,
                   unsigned long long* __restrict__ packed,
                   int D) {
    __shared__ unsigned short sh[49152];       // 96 KiB
    const int tid  = threadIdx.x;
    const int lane = tid & 63;
    const int w    = tid >> 6;                 // 0..7
    const int wr   = w >> 2;                   // 0..1
    const int wc   = w & 3;                    // 0..3
    const long rowbase = (long)blockIdx.x * 256;
    const int  colbase = blockIdx.y * 256;
    const int fr = lane & 15, g = lane >> 4;

    const int sphys = ((fr & 1) * 4 + g) ^ (fr >> 1);      // per-lane 16B slot
    const int abase = wr * 4096 + (fr >> 1) * 64 + sphys * 8;
    const int bbase = 24576 + wc * 2048 + (fr >> 1) * 64 + sphys * 8;

    // A reg-staging: thread owns chunks c = 2*tid + j, row = c>>2, q = c&3
    const int ac0 = 2 * tid, ac1 = 2 * tid + 1;
    const int arow0 = ac0 >> 2, aq0 = ac0 & 3;
    const int arow1 = ac1 >> 2, aq1 = ac1 & 3;
    const unsigned short* gA0 = Xb + (rowbase + arow0) * D + aq0 * 8;
    const unsigned short* gA1 = Xb + (rowbase + arow1) * D + aq1 * 8;
    const int awr0 = (arow0 >> 1) * 64 + ((((arow0 & 1) * 4 + aq0) ^ ((arow0 >> 1) & 7)) * 8);
    const int awr1 = (arow1 >> 1) * 64 + ((((arow1 & 1) * 4 + aq1) ^ ((arow1 >> 1) & 7)) * 8);

    // B gload_lds: physical chunk p = w*128 + j*64 + lane (linear dest),
    // global source pre-swizzled to realize the XOR layout.
    const int p0 = w * 128 + lane, p1 = w * 128 + 64 + lane;
    const int l0 = p0 >> 3, sl0 = (p0 & 7) ^ (l0 & 7);
    const int l1 = p1 >> 3, sl1 = (p1 & 7) ^ (l1 & 7);
    const unsigned short* gB0 = Cb + ((long)colbase + l0 * 2 + (sl0 >> 2)) * D + (sl0 & 3) * 8;
    const unsigned short* gB1 = Cb + ((long)colbase + l1 * 2 + (sl1 >> 2)) * D + (sl1 & 3) * 8;

    f32x4 acc[8][4] = {};
    bf16x8 a03A[4], a03B[4], a47[4], b[4];
    uint4 aregA[2], aregB[2];

    auto loadA = [&](int kt, uint4 (&r)[2]) {
        r[0] = *(const uint4*)(gA0 + (long)kt * 32);
        r[1] = *(const uint4*)(gA1 + (long)kt * 32);
    };
    auto writeA = [&](int kt, uint4 (&r)[2]) {
        const int s = (kt % 3) * 8192;
        *(uint4*)&sh[s + awr0] = r[0];
        *(uint4*)&sh[s + awr1] = r[1];
    };
    auto gloadB = [&](int kt) {
        const int s = 24576 + (kt % 3) * 8192;
        gload16(gB0 + (long)kt * 32, sh + s + (w * 128) * 8);
        gload16(gB1 + (long)kt * 32, sh + s + (w * 128 + 64) * 8);
    };

    // ---- prologue ----
    loadA(0, aregA);
    gloadB(0);
    loadA(1, aregB);
    gloadB(1);
    writeA(0, aregA);          // compiler waits A(0); retires in order
    loadA(2, aregA);
    writeA(1, aregB);          // compiler waits A(1) (retires B(0) too)
    asm volatile("s_waitcnt lgkmcnt(0)" ::: "memory");
    BARRIER();
    #pragma unroll
    for (int m = 0; m < 4; ++m) a03A[m] = *(const bf16x8*)&sh[abase + m * 512];  // a03(0)

    auto tile = [&](int t, bf16x8 (&acur)[4], bf16x8 (&anxt)[4],
                    uint4 (&wreg)[2], uint4 (&lreg)[2],
                    bool doB, bool doA, bool doW, bool doAhead, bool vm0, bool doBar) {
        const int sb = (t % 3) * 8192;
        if (doB) gloadB(t + 2);
        if (doA) loadA(t + 3, lreg);
        #pragma unroll
        for (int n = 0; n < 4; ++n) b[n] = *(const bf16x8*)&sh[bbase + sb + n * 512];
        #pragma unroll
        for (int m = 0; m < 4; ++m) a47[m] = *(const bf16x8*)&sh[abase + sb + (m + 4) * 512];
        if (doAhead) {
            const int sn = ((t + 1) % 3) * 8192;
            #pragma unroll
            for (int m = 0; m < 4; ++m) anxt[m] = *(const bf16x8*)&sh[abase + sn + m * 512];
        }
        __builtin_amdgcn_s_setprio(1);
        #pragma unroll
        for (int m = 0; m < 4; ++m)
            #pragma unroll
            for (int n = 0; n < 4; ++n)
                acc[m][n] = __builtin_amdgcn_mfma_f32_16x16x32_bf16(acur[m], b[n], acc[m][n], 0, 0, 0);
        #pragma unroll
        for (int m = 0; m < 4; ++m)
            #pragma unroll
            for (int n = 0; n < 4; ++n)
                acc[m + 4][n] = __builtin_amdgcn_mfma_f32_16x16x32_bf16(a47[m], b[n], acc[m + 4][n], 0, 0, 0);
        __builtin_amdgcn_s_setprio(0);
        if (doW) writeA(t + 2, wreg);       // compiler-derived vmcnt before use
        if (vm0) asm volatile("s_waitcnt vmcnt(0)" ::: "memory");
        if (doBar) {
            asm volatile("s_waitcnt lgkmcnt(0)" ::: "memory");
            BARRIER();
        }
    };

    for (int tp = 0; tp < (NT - 4) / 2; ++tp) {          // t = 0 .. NT-6 paired
        const int t = tp * 2;
        tile(t,     a03A, a03B, aregA, aregB, true, true, true, true, false, true);
        tile(t + 1, a03B, a03A, aregB, aregA, true, true, true, true, false, true);
    }
    tile(NT - 4, a03A, a03B, aregA, aregB, true,  true,  true,  true,  false, true);
    tile(NT - 3, a03B, a03A, aregB, aregA, true,  false, true,  true,  false, true);
    tile(NT - 2, a03A, a03B, aregA, aregB, false, false, false, true,  true,  true);
    tile(NT - 1, a03B, a03A, aregB, aregA, false, false, false, false, false, false);

    // ---- argmin epilogue: score = c2[k] - 2*dot.  C/D: col=lane&15, row=g*4+reg ----
    float c2v[4];
    int   kcol[4];
    #pragma unroll
    for (int n = 0; n < 4; ++n) {
        kcol[n] = colbase + wc * 64 + n * 16 + fr;
        c2v[n]  = c2[kcol[n]];
    }
    #pragma unroll
    for (int m = 0; m < 8; ++m) {
        #pragma unroll
        for (int reg = 0; reg < 4; ++reg) {
            unsigned long long best = ~0ull;
            #pragma unroll
            for (int n = 0; n < 4; ++n) {
                float score = c2v[n] - 2.0f * acc[m][n][reg];
                unsigned u = __float_as_uint(score);
                u ^= (u >> 31) ? 0xFFFFFFFFu : 0x80000000u;   // order-preserving map
                unsigned long long cand = ((unsigned long long)u << 32) | (unsigned)kcol[n];
                best = cand < best ? cand : best;
            }
            #pragma unroll
            for (int s = 1; s < 16; s <<= 1) {
                unsigned long long other = __shfl_xor(best, s, 64);
                best = other < best ? other : best;
            }
            if (fr == 0) {
                long row = rowbase + wr * 128 + m * 16 + g * 4 + reg;
                atomicMin(&packed[row], best);   // min is order-independent -> deterministic
            }
        }
    }
}

__global__ void extract16_kernel(const unsigned long long* __restrict__ p,
                                 unsigned short* __restrict__ lab, int n) {
    int i = blockIdx.x * blockDim.x + threadIdx.x;
    if (i < n) lab[i] = (unsigned short)(p[i] & 0xFFFFull);
}

// ---------------- segmented sum: sliced partials (S=4, u16 labels) ----------------
__global__ void segsum_partial_kernel(const unsigned short* __restrict__ lab,
                                      const float* __restrict__ emb,
                                      float* __restrict__ partial,
                                      int* __restrict__ pcount,
                                      int N, int D) {
    const int k   = blockIdx.x;
    const int s   = blockIdx.y;
    const int tid = threadIdx.x;
    const int grp = tid >> 8;
    const int ct  = tid & 255;
    const int lane = tid & 63, w = tid >> 6;

    __shared__ int idxbuf[4096];
    __shared__ int cnts[16];
    __shared__ float4 red[4][256];

    const int slice = N >> 2;
    const int base0 = s * slice;
    int total = 0;
    for (int base = base0; base < base0 + slice; base += 1024) {
        const int n = base + tid;
        const bool m = (lab[n] == (unsigned short)k);
        const unsigned long long bal = __ballot(m);
        if (lane == 0) cnts[w] = (int)__popcll(bal);
        __syncthreads();
        int myoff = total, run = total;
        #pragma unroll
        for (int w2 = 0; w2 < 16; ++w2) {
            if (w2 == w) myoff = run;
            run += cnts[w2];
        }
        if (m) idxbuf[myoff + (int)__popcll(bal & ((1ull << lane) - 1ull))] = n;
        total = run;
        __syncthreads();
    }

    float4 acc = {0.f, 0.f, 0.f, 0.f};
    for (int j = grp; j < total; j += 4) {
        const int row = idxbuf[j];
        const float4 v = *(const float4*)(emb + (long)row * D + ct * 4);
        acc.x += v.x; acc.y += v.y; acc.z += v.z; acc.w += v.w;
    }
    red[grp][ct] = acc;
    __syncthreads();
    if (grp == 0) {
        float4 r = red[0][ct];
        #pragma unroll
        for (int q = 1; q < 4; ++q) {
            const float4 v = red[q][ct];
            r.x += v.x; r.y += v.y; r.z += v.z; r.w += v.w;
        }
        *(float4*)(partial + ((long)(k * 4 + s)) * D + ct * 4) = r;
    }
    if (tid == 0) pcount[k * 4 + s] = total;
}

__global__ void finalize_kernel(const float* __restrict__ partial,
                                const int* __restrict__ pcount,
                                const float* __restrict__ centers,
                                const int* __restrict__ cnt,
                                float* __restrict__ out, int D) {
    const int k = blockIdx.x;
    const int ct = threadIdx.x;
    float4 acc = {0.f, 0.f, 0.f, 0.f};
    int mtot = 0;
    #pragma unroll
    for (int s = 0; s < 4; ++s) {
        const float4 p = *(const float4*)(partial + ((long)(k * 4 + s)) * D + ct * 4);
        acc.x += p.x; acc.y += p.y; acc.z += p.z; acc.w += p.w;
        mtot += pcount[k * 4 + s];
    }
    const float4 cv = *(const float4*)(centers + (long)k * D + ct * 4);
    float4 o;
    if (mtot > 0) {
        float ccn = 0.5f * (float)cnt[k] + 0.5f * (float)mtot;
        float lr  = 1.0f / (ccn + 1.0f);
        float im  = 1.0f / (float)mtot;
        float om  = 1.0f - lr;
        o.x = om * cv.x + lr * (acc.x * im);
        o.y = om * cv.y + lr * (acc.y * im);
        o.z = om * cv.z + lr * (acc.z * im);
        o.w = om * cv.w + lr * (acc.w * im);
    } else {
        o = cv;
    }
    *(float4*)(out + (long)k * D + ct * 4) = o;
}

// ---------------- launch ----------------

extern "C" void kernel_launch(void* const* d_in, const int* in_sizes, int n_in,
                              void* d_out, int out_size, void* d_ws, size_t ws_size,
                              hipStream_t stream) {
    const float* emb = (const float*)d_in[0];
    const float* cen = (const float*)d_in[1];
    const int*   cnt = (const int*)d_in[2];
    float* out = (float*)d_out;
    const int K = in_sizes[2];
    const int D = in_sizes[1] / K;      // 1024
    const int N = in_sizes[0] / D;      // 16384

    char* ws = (char*)d_ws;
    size_t xb_bytes = (size_t)N * D * 2;            // 32 MB
    size_t cb_bytes = (size_t)K * D * 2;            // 2 MB
    unsigned short* Xb = (unsigned short*)ws;
    unsigned short* Cb = (unsigned short*)(ws + xb_bytes);
    float* c2 = (float*)(ws + xb_bytes + cb_bytes);
    unsigned long long* packed = (unsigned long long*)(ws + xb_bytes + cb_bytes + (size_t)K * 4);
    unsigned short* lab16 = (unsigned short*)(ws + xb_bytes + cb_bytes + (size_t)K * 4 + (size_t)N * 8);
    int* pcount = (int*)(ws + xb_bytes + cb_bytes + (size_t)K * 4 + (size_t)N * 8 + (size_t)N * 2);
    float* partial = (float*)ws;   // aliases Xb (dead after gemm)

    int total8 = N * D / 8;
    conv_x_kernel<<<dim3((total8 + 255) / 256), dim3(256), 0, stream>>>(emb, Xb, total8);
    conv_c_kernel<<<dim3(K), dim3(256), 0, stream>>>(cen, Cb, c2, packed, N, D);
    gemm_argmin_kernel<32><<<dim3(N / 256, K / 256), dim3(512), 0, stream>>>(Xb, Cb, c2, packed, D);
    extract16_kernel<<<dim3((N + 255) / 256), dim3(256), 0, stream>>>(packed, lab16, N);
    segsum_partial_kernel<<<dim3(K, 4), dim3(1024), 0, stream>>>(lab16, emb, partial, pcount, N, D);
    finalize_kernel<<<dim3(K), dim3(256), 0, stream>>>(partial, pcount, cen, cnt, out, D);
}

// Round 9
// 104.556 us; speedup vs baseline: 6.0088x; 1.1306x over previous
//
#include <hip/hip_runtime.h>

typedef __attribute__((ext_vector_type(8))) short bf16x8;
typedef __attribute__((ext_vector_type(4))) float f32x4;

__device__ __forceinline__ unsigned short f2bf(float f) {
    unsigned u = __float_as_uint(f);
    unsigned r = (u + 0x7FFFu + ((u >> 16) & 1u)) >> 16;   // RNE
    return (unsigned short)r;
}

__device__ __forceinline__ void gload16(const unsigned short* g, unsigned short* l) {
    __builtin_amdgcn_global_load_lds((const __attribute__((address_space(1))) void*)g,
                                     (__attribute__((address_space(3))) void*)l, 16, 0, 0);
}

#define BARRIER() do { asm volatile("" ::: "memory"); __builtin_amdgcn_s_barrier(); asm volatile("" ::: "memory"); } while (0)

// ---------------- conversion kernels ----------------

__global__ void conv_x_kernel(const float* __restrict__ x, unsigned short* __restrict__ xb, int total8) {
    int i = blockIdx.x * blockDim.x + threadIdx.x;
    if (i >= total8) return;
    const float4* xv = (const float4*)x;
    float4 a = xv[(size_t)i * 2];
    float4 b = xv[(size_t)i * 2 + 1];
    uint4 o;
    o.x = (unsigned)f2bf(a.x) | ((unsigned)f2bf(a.y) << 16);
    o.y = (unsigned)f2bf(a.z) | ((unsigned)f2bf(a.w) << 16);
    o.z = (unsigned)f2bf(b.x) | ((unsigned)f2bf(b.y) << 16);
    o.w = (unsigned)f2bf(b.z) | ((unsigned)f2bf(b.w) << 16);
    ((uint4*)xb)[i] = o;
}

__global__ void conv_c_kernel(const float* __restrict__ c, unsigned short* __restrict__ cb,
                              float* __restrict__ c2, unsigned long long* __restrict__ packed,
                              int N, int D) {
    int k = blockIdx.x;
    int tid = threadIdx.x;                      // 256 threads, 4 elems each
    const float4 v = ((const float4*)(c + (long)k * D))[tid];
    uint2 o;
    o.x = (unsigned)f2bf(v.x) | ((unsigned)f2bf(v.y) << 16);
    o.y = (unsigned)f2bf(v.z) | ((unsigned)f2bf(v.w) << 16);
    ((uint2*)(cb + (long)k * D))[tid] = o;
    float s = v.x * v.x + v.y * v.y + v.z * v.z + v.w * v.w;
    #pragma unroll
    for (int d = 1; d < 64; d <<= 1) s += __shfl_xor(s, d, 64);
    __shared__ float wsum[4];
    int lane = tid & 63, w = tid >> 6;
    if (lane == 0) wsum[w] = s;
    __syncthreads();
    if (tid == 0) c2[k] = wsum[0] + wsum[1] + wsum[2] + wsum[3];
    int gid = k * 256 + tid;
    if (gid < N) packed[gid] = ~0ull;
}

// ------------- GEMM + argmin (verbatim round-6 ring-of-4, known 43.2us) -------------
__global__ void __launch_bounds__(512, 2)
gemm_argmin_kernel(const unsigned short* __restrict__ Xb,
                   const unsigned short* __restrict__ Cb,
                   const float* __restrict__ c2,
                   unsigned long long* __restrict__ packed,
                   int D, int nt) {
    __shared__ unsigned short sh[65536];       // 128 KiB
    const int tid  = threadIdx.x;
    const int lane = tid & 63;
    const int w    = tid >> 6;
    const int wr   = w >> 2;
    const int wc   = w & 3;
    const long rowbase = (long)blockIdx.x * 256;
    const int  colbase = blockIdx.y * 256;
    const int fr = lane & 15;
    const int g  = lane >> 4;

    const int c0 = tid, c1 = 512 + tid;
    const unsigned short* gA0 = Xb + (rowbase + (c0 >> 2)) * D + (c0 & 3) * 8;
    const unsigned short* gA1 = Xb + (rowbase + (c1 >> 2)) * D + (c1 & 3) * 8;
    const unsigned short* gB0 = Cb + ((long)colbase + (c0 >> 2)) * D + (c0 & 3) * 8;
    const unsigned short* gB1 = Cb + ((long)colbase + (c1 >> 2)) * D + (c1 & 3) * 8;

    f32x4 acc[8][4] = {};
    bf16x8 a[8], b[4];

    auto stage = [&](int kt) {
        const int s = (kt & 3) * 8192;
        const long ko = (long)kt * 32;
        gload16(gA0 + ko, sh + s + c0 * 8);
        gload16(gA1 + ko, sh + s + c1 * 8);
        gload16(gB0 + ko, sh + 32768 + s + c0 * 8);
        gload16(gB1 + ko, sh + 32768 + s + c1 * 8);
    };

    stage(0); stage(1); stage(2);
    asm volatile("s_waitcnt vmcnt(8)" ::: "memory");
    BARRIER();

    for (int t = 0; t < nt; ++t) {
        const int sb = (t & 3) * 8192;
        if (t + 3 < nt) stage(t + 3);
        const int ar = sb + (wr * 128 + fr) * 32 + g * 8;
        #pragma unroll
        for (int m = 0; m < 8; ++m) a[m] = *(const bf16x8*)&sh[ar + m * 512];
        const int br = 32768 + sb + (wc * 64 + fr) * 32 + g * 8;
        #pragma unroll
        for (int n = 0; n < 4; ++n) b[n] = *(const bf16x8*)&sh[br + n * 512];
        asm volatile("s_waitcnt vmcnt(8) lgkmcnt(0)" ::: "memory");
        BARRIER();
        __builtin_amdgcn_s_setprio(1);
        #pragma unroll
        for (int m = 0; m < 8; ++m)
            #pragma unroll
            for (int n = 0; n < 4; ++n)
                acc[m][n] = __builtin_amdgcn_mfma_f32_16x16x32_bf16(a[m], b[n], acc[m][n], 0, 0, 0);
        __builtin_amdgcn_s_setprio(0);
    }

    float c2v[4];
    int   kcol[4];
    #pragma unroll
    for (int n = 0; n < 4; ++n) {
        kcol[n] = colbase + wc * 64 + n * 16 + fr;
        c2v[n]  = c2[kcol[n]];
    }
    #pragma unroll
    for (int m = 0; m < 8; ++m) {
        #pragma unroll
        for (int reg = 0; reg < 4; ++reg) {
            unsigned long long best = ~0ull;
            #pragma unroll
            for (int n = 0; n < 4; ++n) {
                float score = c2v[n] - 2.0f * acc[m][n][reg];
                unsigned u = __float_as_uint(score);
                u ^= (u >> 31) ? 0xFFFFFFFFu : 0x80000000u;   // order-preserving map
                unsigned long long cand = ((unsigned long long)u << 32) | (unsigned)kcol[n];
                best = cand < best ? cand : best;
            }
            #pragma unroll
            for (int s = 1; s < 16; s <<= 1) {
                unsigned long long other = __shfl_xor(best, s, 64);
                best = other < best ? other : best;
            }
            if (fr == 0) {
                long row = rowbase + wr * 128 + m * 16 + g * 4 + reg;
                atomicMin(&packed[row], best);   // min is order-independent -> deterministic
            }
        }
    }
}

__global__ void extract16_kernel(const unsigned long long* __restrict__ p,
                                 unsigned short* __restrict__ lab, int n) {
    int i = blockIdx.x * blockDim.x + threadIdx.x;
    if (i < n) lab[i] = (unsigned short)(p[i] & 0xFFFFull);
}

// ---------------- segmented sum: sliced partials (S=8, u16 labels) ----------------
// grid (K, 8); block 1024 = 4 row-groups x 256 col-threads.  Ballot-compacted
// index list per (k,s) slice (deterministic), groups gather every 4th row,
// fixed-order LDS reduce -> fp32 partial [k][8][D] + count.
__global__ void segsum_partial_kernel(const unsigned short* __restrict__ lab,
                                      const float* __restrict__ emb,
                                      float* __restrict__ partial,
                                      int* __restrict__ pcount,
                                      int N, int D) {
    const int k   = blockIdx.x;
    const int s   = blockIdx.y;
    const int tid = threadIdx.x;
    const int grp = tid >> 8;
    const int ct  = tid & 255;
    const int lane = tid & 63, w = tid >> 6;

    __shared__ int idxbuf[2048];
    __shared__ int cnts[16];
    __shared__ float4 red[4][256];

    const int slice = N >> 3;             // 2048
    const int base0 = s * slice;
    int total = 0;
    for (int base = base0; base < base0 + slice; base += 1024) {
        const int n = base + tid;
        const bool m = (lab[n] == (unsigned short)k);
        const unsigned long long bal = __ballot(m);
        if (lane == 0) cnts[w] = (int)__popcll(bal);
        __syncthreads();
        int myoff = total, run = total;
        #pragma unroll
        for (int w2 = 0; w2 < 16; ++w2) {
            if (w2 == w) myoff = run;
            run += cnts[w2];
        }
        if (m) idxbuf[myoff + (int)__popcll(bal & ((1ull << lane) - 1ull))] = n;
        total = run;
        __syncthreads();
    }

    float4 acc = {0.f, 0.f, 0.f, 0.f};
    for (int j = grp; j < total; j += 4) {
        const int row = idxbuf[j];
        const float4 v = *(const float4*)(emb + (long)row * D + ct * 4);
        acc.x += v.x; acc.y += v.y; acc.z += v.z; acc.w += v.w;
    }
    red[grp][ct] = acc;
    __syncthreads();
    if (grp == 0) {
        float4 r = red[0][ct];
        #pragma unroll
        for (int q = 1; q < 4; ++q) {
            const float4 v = red[q][ct];
            r.x += v.x; r.y += v.y; r.z += v.z; r.w += v.w;
        }
        *(float4*)(partial + ((long)(k * 8 + s)) * D + ct * 4) = r;
    }
    if (tid == 0) pcount[k * 8 + s] = total;
}

// one block per cluster: reduce 8 slice partials (fixed order) + EMA finalize
__global__ void finalize_kernel(const float* __restrict__ partial,
                                const int* __restrict__ pcount,
                                const float* __restrict__ centers,
                                const int* __restrict__ cnt,
                                float* __restrict__ out, int D) {
    const int k = blockIdx.x;
    const int ct = threadIdx.x;           // 256 threads, 4 cols each
    float4 acc = {0.f, 0.f, 0.f, 0.f};
    int mtot = 0;
    #pragma unroll
    for (int s = 0; s < 8; ++s) {
        const float4 p = *(const float4*)(partial + ((long)(k * 8 + s)) * D + ct * 4);
        acc.x += p.x; acc.y += p.y; acc.z += p.z; acc.w += p.w;
        mtot += pcount[k * 8 + s];
    }
    const float4 cv = *(const float4*)(centers + (long)k * D + ct * 4);
    float4 o;
    if (mtot > 0) {
        float ccn = 0.5f * (float)cnt[k] + 0.5f * (float)mtot;
        float lr  = 1.0f / (ccn + 1.0f);
        float im  = 1.0f / (float)mtot;
        float om  = 1.0f - lr;
        o.x = om * cv.x + lr * (acc.x * im);
        o.y = om * cv.y + lr * (acc.y * im);
        o.z = om * cv.z + lr * (acc.z * im);
        o.w = om * cv.w + lr * (acc.w * im);
    } else {
        o = cv;
    }
    *(float4*)(out + (long)k * D + ct * 4) = o;
}

// ---------------- launch ----------------

extern "C" void kernel_launch(void* const* d_in, const int* in_sizes, int n_in,
                              void* d_out, int out_size, void* d_ws, size_t ws_size,
                              hipStream_t stream) {
    const float* emb = (const float*)d_in[0];
    const float* cen = (const float*)d_in[1];
    const int*   cnt = (const int*)d_in[2];
    float* out = (float*)d_out;
    const int K = in_sizes[2];
    const int D = in_sizes[1] / K;      // 1024
    const int N = in_sizes[0] / D;      // 16384

    char* ws = (char*)d_ws;
    size_t xb_bytes = (size_t)N * D * 2;            // 32 MB
    size_t cb_bytes = (size_t)K * D * 2;            // 2 MB
    unsigned short* Xb = (unsigned short*)ws;
    unsigned short* Cb = (unsigned short*)(ws + xb_bytes);
    float* c2 = (float*)(ws + xb_bytes + cb_bytes);
    unsigned long long* packed = (unsigned long long*)(ws + xb_bytes + cb_bytes + (size_t)K * 4);
    unsigned short* lab16 = (unsigned short*)(ws + xb_bytes + cb_bytes + (size_t)K * 4 + (size_t)N * 8);
    int* pcount = (int*)(ws + xb_bytes + cb_bytes + (size_t)K * 4 + (size_t)N * 8 + (size_t)N * 2);
    // partial [K][8][D] fp32 = 32 MB aliases the Xb region exactly (Xb dead after gemm).
    float* partial = (float*)ws;

    int total8 = N * D / 8;
    conv_x_kernel<<<dim3((total8 + 255) / 256), dim3(256), 0, stream>>>(emb, Xb, total8);
    conv_c_kernel<<<dim3(K), dim3(256), 0, stream>>>(cen, Cb, c2, packed, N, D);
    gemm_argmin_kernel<<<dim3(N / 256, K / 256), dim3(512), 0, stream>>>(Xb, Cb, c2, packed, D, D / 32);
    extract16_kernel<<<dim3((N + 255) / 256), dim3(256), 0, stream>>>(packed, lab16, N);
    segsum_partial_kernel<<<dim3(K, 8), dim3(1024), 0, stream>>>(lab16, emb, partial, pcount, N, D);
    finalize_kernel<<<dim3(K), dim3(256), 0, stream>>>(partial, pcount, cen, cnt, out, D);
}

// Round 10
// 100.083 us; speedup vs baseline: 6.2773x; 1.0447x over previous
//
#include <hip/hip_runtime.h>

typedef __attribute__((ext_vector_type(8))) short bf16x8;
typedef __attribute__((ext_vector_type(4))) float f32x4;

__device__ __forceinline__ unsigned short f2bf(float f) {
    unsigned u = __float_as_uint(f);
    unsigned r = (u + 0x7FFFu + ((u >> 16) & 1u)) >> 16;   // RNE
    return (unsigned short)r;
}

__device__ __forceinline__ void gload16(const unsigned short* g, unsigned short* l) {
    __builtin_amdgcn_global_load_lds((const __attribute__((address_space(1))) void*)g,
                                     (__attribute__((address_space(3))) void*)l, 16, 0, 0);
}

#define BARRIER() do { asm volatile("" ::: "memory"); __builtin_amdgcn_s_barrier(); asm volatile("" ::: "memory"); } while (0)

// ---------------- fused prep: conv_x + conv_c + c2 + packed-init ----------------
// blocks [0, nxb)            : X fp32 -> bf16 (8 elems/thread)
// blocks [nxb, nxb + K)      : one block per center row: bf16 convert + exact
//                              fp32 ||c||^2 + packed init
__global__ void prep_kernel(const float* __restrict__ x, unsigned short* __restrict__ xb,
                            const float* __restrict__ c, unsigned short* __restrict__ cb,
                            float* __restrict__ c2, unsigned long long* __restrict__ packed,
                            int total8, int nxb, int N, int D) {
    const int bid = blockIdx.x;
    const int tid = threadIdx.x;
    if (bid < nxb) {
        int i = bid * 256 + tid;
        if (i >= total8) return;
        const float4* xv = (const float4*)x;
        float4 a = xv[(size_t)i * 2];
        float4 b = xv[(size_t)i * 2 + 1];
        uint4 o;
        o.x = (unsigned)f2bf(a.x) | ((unsigned)f2bf(a.y) << 16);
        o.y = (unsigned)f2bf(a.z) | ((unsigned)f2bf(a.w) << 16);
        o.z = (unsigned)f2bf(b.x) | ((unsigned)f2bf(b.y) << 16);
        o.w = (unsigned)f2bf(b.z) | ((unsigned)f2bf(b.w) << 16);
        ((uint4*)xb)[i] = o;
        return;
    }
    const int k = bid - nxb;
    const float4 v = ((const float4*)(c + (long)k * D))[tid];
    uint2 o;
    o.x = (unsigned)f2bf(v.x) | ((unsigned)f2bf(v.y) << 16);
    o.y = (unsigned)f2bf(v.z) | ((unsigned)f2bf(v.w) << 16);
    ((uint2*)(cb + (long)k * D))[tid] = o;
    float s = v.x * v.x + v.y * v.y + v.z * v.z + v.w * v.w;
    #pragma unroll
    for (int d = 1; d < 64; d <<= 1) s += __shfl_xor(s, d, 64);
    __shared__ float wsum[4];
    int lane = tid & 63, w = tid >> 6;
    if (lane == 0) wsum[w] = s;
    __syncthreads();
    if (tid == 0) c2[k] = wsum[0] + wsum[1] + wsum[2] + wsum[3];
    int gid = k * 256 + tid;
    if (gid < N) packed[gid] = ~0ull;
}

// ------------- GEMM + argmin (verbatim ring-of-4, known 43.2us) -------------
__global__ void __launch_bounds__(512, 2)
gemm_argmin_kernel(const unsigned short* __restrict__ Xb,
                   const unsigned short* __restrict__ Cb,
                   const float* __restrict__ c2,
                   unsigned long long* __restrict__ packed,
                   int D, int nt) {
    __shared__ unsigned short sh[65536];       // 128 KiB
    const int tid  = threadIdx.x;
    const int lane = tid & 63;
    const int w    = tid >> 6;
    const int wr   = w >> 2;
    const int wc   = w & 3;
    const long rowbase = (long)blockIdx.x * 256;
    const int  colbase = blockIdx.y * 256;
    const int fr = lane & 15;
    const int g  = lane >> 4;

    const int c0 = tid, c1 = 512 + tid;
    const unsigned short* gA0 = Xb + (rowbase + (c0 >> 2)) * D + (c0 & 3) * 8;
    const unsigned short* gA1 = Xb + (rowbase + (c1 >> 2)) * D + (c1 & 3) * 8;
    const unsigned short* gB0 = Cb + ((long)colbase + (c0 >> 2)) * D + (c0 & 3) * 8;
    const unsigned short* gB1 = Cb + ((long)colbase + (c1 >> 2)) * D + (c1 & 3) * 8;

    f32x4 acc[8][4] = {};
    bf16x8 a[8], b[4];

    auto stage = [&](int kt) {
        const int s = (kt & 3) * 8192;
        const long ko = (long)kt * 32;
        gload16(gA0 + ko, sh + s + c0 * 8);
        gload16(gA1 + ko, sh + s + c1 * 8);
        gload16(gB0 + ko, sh + 32768 + s + c0 * 8);
        gload16(gB1 + ko, sh + 32768 + s + c1 * 8);
    };

    stage(0); stage(1); stage(2);
    asm volatile("s_waitcnt vmcnt(8)" ::: "memory");
    BARRIER();

    for (int t = 0; t < nt; ++t) {
        const int sb = (t & 3) * 8192;
        if (t + 3 < nt) stage(t + 3);
        const int ar = sb + (wr * 128 + fr) * 32 + g * 8;
        #pragma unroll
        for (int m = 0; m < 8; ++m) a[m] = *(const bf16x8*)&sh[ar + m * 512];
        const int br = 32768 + sb + (wc * 64 + fr) * 32 + g * 8;
        #pragma unroll
        for (int n = 0; n < 4; ++n) b[n] = *(const bf16x8*)&sh[br + n * 512];
        asm volatile("s_waitcnt vmcnt(8) lgkmcnt(0)" ::: "memory");
        BARRIER();
        __builtin_amdgcn_s_setprio(1);
        #pragma unroll
        for (int m = 0; m < 8; ++m)
            #pragma unroll
            for (int n = 0; n < 4; ++n)
                acc[m][n] = __builtin_amdgcn_mfma_f32_16x16x32_bf16(a[m], b[n], acc[m][n], 0, 0, 0);
        __builtin_amdgcn_s_setprio(0);
    }

    float c2v[4];
    int   kcol[4];
    #pragma unroll
    for (int n = 0; n < 4; ++n) {
        kcol[n] = colbase + wc * 64 + n * 16 + fr;
        c2v[n]  = c2[kcol[n]];
    }
    #pragma unroll
    for (int m = 0; m < 8; ++m) {
        #pragma unroll
        for (int reg = 0; reg < 4; ++reg) {
            unsigned long long best = ~0ull;
            #pragma unroll
            for (int n = 0; n < 4; ++n) {
                float score = c2v[n] - 2.0f * acc[m][n][reg];
                unsigned u = __float_as_uint(score);
                u ^= (u >> 31) ? 0xFFFFFFFFu : 0x80000000u;   // order-preserving map
                unsigned long long cand = ((unsigned long long)u << 32) | (unsigned)kcol[n];
                best = cand < best ? cand : best;
            }
            #pragma unroll
            for (int s = 1; s < 16; s <<= 1) {
                unsigned long long other = __shfl_xor(best, s, 64);
                best = other < best ? other : best;
            }
            if (fr == 0) {
                long row = rowbase + wr * 128 + m * 16 + g * 4 + reg;
                atomicMin(&packed[row], best);   // min is order-independent -> deterministic
            }
        }
    }
}

// ---------------- segmented sum: sliced partials (S=4, reads packed directly) ----------------
// grid (K, 4); block 1024 = 4 row-groups x 256 col-threads.  Ballot-compacted
// index list per (k,s) slice (deterministic), groups gather every 4th row,
// fixed-order LDS reduce -> fp32 partial [k][4][D] + count.  packed is 128KB ->
// L2-resident; label = low bits of packed[n].
__global__ void segsum_partial_kernel(const unsigned long long* __restrict__ packed,
                                      const float* __restrict__ emb,
                                      float* __restrict__ partial,
                                      int* __restrict__ pcount,
                                      int N, int D) {
    const int k   = blockIdx.x;
    const int s   = blockIdx.y;
    const int tid = threadIdx.x;
    const int grp = tid >> 8;
    const int ct  = tid & 255;
    const int lane = tid & 63, w = tid >> 6;

    __shared__ int idxbuf[4096];
    __shared__ int cnts[16];
    __shared__ float4 red[4][256];

    const int slice = N >> 2;             // 4096
    const int base0 = s * slice;
    int total = 0;
    for (int base = base0; base < base0 + slice; base += 1024) {
        const int n = base + tid;
        const bool m = ((unsigned)(packed[n] & 0xFFFFFFFFull) == (unsigned)k);
        const unsigned long long bal = __ballot(m);
        if (lane == 0) cnts[w] = (int)__popcll(bal);
        __syncthreads();
        int myoff = total, run = total;
        #pragma unroll
        for (int w2 = 0; w2 < 16; ++w2) {
            if (w2 == w) myoff = run;
            run += cnts[w2];
        }
        if (m) idxbuf[myoff + (int)__popcll(bal & ((1ull << lane) - 1ull))] = n;
        total = run;
        __syncthreads();
    }

    float4 acc = {0.f, 0.f, 0.f, 0.f};
    for (int j = grp; j < total; j += 4) {
        const int row = idxbuf[j];
        const float4 v = *(const float4*)(emb + (long)row * D + ct * 4);
        acc.x += v.x; acc.y += v.y; acc.z += v.z; acc.w += v.w;
    }
    red[grp][ct] = acc;
    __syncthreads();
    if (grp == 0) {
        float4 r = red[0][ct];
        #pragma unroll
        for (int q = 1; q < 4; ++q) {
            const float4 v = red[q][ct];
            r.x += v.x; r.y += v.y; r.z += v.z; r.w += v.w;
        }
        *(float4*)(partial + ((long)(k * 4 + s)) * D + ct * 4) = r;
    }
    if (tid == 0) pcount[k * 4 + s] = total;
}

// one block per cluster: reduce 4 slice partials (fixed order) + EMA finalize
__global__ void finalize_kernel(const float* __restrict__ partial,
                                const int* __restrict__ pcount,
                                const float* __restrict__ centers,
                                const int* __restrict__ cnt,
                                float* __restrict__ out, int D) {
    const int k = blockIdx.x;
    const int ct = threadIdx.x;           // 256 threads, 4 cols each
    float4 acc = {0.f, 0.f, 0.f, 0.f};
    int mtot = 0;
    #pragma unroll
    for (int s = 0; s < 4; ++s) {
        const float4 p = *(const float4*)(partial + ((long)(k * 4 + s)) * D + ct * 4);
        acc.x += p.x; acc.y += p.y; acc.z += p.z; acc.w += p.w;
        mtot += pcount[k * 4 + s];
    }
    const float4 cv = *(const float4*)(centers + (long)k * D + ct * 4);
    float4 o;
    if (mtot > 0) {
        float ccn = 0.5f * (float)cnt[k] + 0.5f * (float)mtot;
        float lr  = 1.0f / (ccn + 1.0f);
        float im  = 1.0f / (float)mtot;
        float om  = 1.0f - lr;
        o.x = om * cv.x + lr * (acc.x * im);
        o.y = om * cv.y + lr * (acc.y * im);
        o.z = om * cv.z + lr * (acc.z * im);
        o.w = om * cv.w + lr * (acc.w * im);
    } else {
        o = cv;
    }
    *(float4*)(out + (long)k * D + ct * 4) = o;
}

// ---------------- launch ----------------

extern "C" void kernel_launch(void* const* d_in, const int* in_sizes, int n_in,
                              void* d_out, int out_size, void* d_ws, size_t ws_size,
                              hipStream_t stream) {
    const float* emb = (const float*)d_in[0];
    const float* cen = (const float*)d_in[1];
    const int*   cnt = (const int*)d_in[2];
    float* out = (float*)d_out;
    const int K = in_sizes[2];
    const int D = in_sizes[1] / K;      // 1024
    const int N = in_sizes[0] / D;      // 16384

    char* ws = (char*)d_ws;
    size_t xb_bytes = (size_t)N * D * 2;            // 32 MB
    size_t cb_bytes = (size_t)K * D * 2;            // 2 MB
    unsigned short* Xb = (unsigned short*)ws;
    unsigned short* Cb = (unsigned short*)(ws + xb_bytes);
    float* c2 = (float*)(ws + xb_bytes + cb_bytes);
    unsigned long long* packed = (unsigned long long*)(ws + xb_bytes + cb_bytes + (size_t)K * 4);
    int* pcount = (int*)(ws + xb_bytes + cb_bytes + (size_t)K * 4 + (size_t)N * 8);
    // partial [K][4][D] fp32 = 16 MB aliases the Xb region (dead after gemm).
    float* partial = (float*)ws;

    const int total8 = N * D / 8;                   // 2M
    const int nxb = (total8 + 255) / 256;           // 8192
    prep_kernel<<<dim3(nxb + K), dim3(256), 0, stream>>>(emb, Xb, cen, Cb, c2, packed, total8, nxb, N, D);
    gemm_argmin_kernel<<<dim3(N / 256, K / 256), dim3(512), 0, stream>>>(Xb, Cb, c2, packed, D, D / 32);
    segsum_partial_kernel<<<dim3(K, 4), dim3(1024), 0, stream>>>(packed, emb, partial, pcount, N, D);
    finalize_kernel<<<dim3(K), dim3(256), 0, stream>>>(partial, pcount, cen, cnt, out, D);
}